// Round 2
// baseline (124.803 us; speedup 1.0000x reference)
//
#include <hip/hip_runtime.h>
#include <math.h>

// TV-1D prox via FGP on the dual, 30 fixed iterations.
// One wave64 per row (256 elems): lane l owns elements [4l..4l+3] of x,y,u
// entirely in registers. 2 shuffles per iteration for the +/-1 neighbor
// stencil. Momentum coefficients precomputed on host into kernargs.

constexpr int N_ITERS = 30;

struct Coefs { float c[N_ITERS]; };

__global__ __launch_bounds__(256, 8)
void tv1d_prox_kernel(const float* __restrict__ x,
                      const float* __restrict__ lmbd_param,
                      float* __restrict__ out,
                      Coefs co)
{
    const int lane = threadIdx.x & 63;
    const int wave = threadIdx.x >> 6;
    const int row  = (blockIdx.x << 2) | wave;      // 32768 rows total
    const int chan = (row >> 7) & 31;               // dims (8,32,128,256)

    const float p    = lmbd_param[chan];
    const float lam  = log1pf(expf(p));             // softplus (p ~ -1, stable)
    const float nlam = -lam;

    // coalesced float4 load: lane l reads 16B at row*1KB + 16*l
    const float4 xv = reinterpret_cast<const float4*>(x)[(row << 6) + lane];
    const float x0 = xv.x, x1 = xv.y, x2 = xv.z, x3 = xv.w;
    // halo x[4l+4] (lane 63 gets garbage; only feeds the masked dummy u slot)
    const float x4 = __shfl_down(x0, 1);

    const bool l0  = (lane == 0);
    const bool l63 = (lane == 63);

    // y = dual iterate, u = previous accepted dual point; u index 255 is a
    // dummy slot on lane 63 kept identically 0.
    float y0 = 0.f, y1 = 0.f, y2 = 0.f, y3 = 0.f;
    float u0 = 0.f, u1 = 0.f, u2 = 0.f, u3 = 0.f;

#pragma unroll
    for (int it = 0; it < N_ITERS; ++it) {
        float ypl = __shfl_up(y3, 1);               // y[4l-1]
        float ynf = __shfl_down(y0, 1);             // y[4l+4]
        ypl = l0 ? 0.f : ypl;                       // Dt boundary: y[-1] := 0

        // w = x - Dt(y);  w[i] = x[i] - y[i-1] + y[i]  (y[255] dummy = 0 on l63)
        const float w0 = x0 - ypl + y0;
        const float w1 = x1 - y0 + y1;
        const float w2 = x2 - y1 + y2;
        const float w3 = x3 - y2 + y3;
        const float w4 = x4 - y3 + ynf;             // halo w[4l+4]

        // u = clip(y + 0.25*(w[j+1]-w[j]), -lam, lam)   (grad = w[j]-w[j+1])
        float v0 = y0 + 0.25f * (w1 - w0);
        float v1 = y1 + 0.25f * (w2 - w1);
        float v2 = y2 + 0.25f * (w3 - w2);
        float v3 = y3 + 0.25f * (w4 - w3);
        v0 = fminf(fmaxf(v0, nlam), lam);           // v_med3
        v1 = fminf(fmaxf(v1, nlam), lam);
        v2 = fminf(fmaxf(v2, nlam), lam);
        v3 = fminf(fmaxf(v3, nlam), lam);
        v3 = l63 ? 0.f : v3;                        // keep dummy slot at 0

        // y_next = v + c*(v - u_prev);  c precomputed (c[0] = 0)
        const float c = co.c[it];
        y0 = v0 + c * (v0 - u0);
        y1 = v1 + c * (v1 - u1);
        y2 = v2 + c * (v2 - u2);
        y3 = v3 + c * (v3 - u3);
        u0 = v0; u1 = v1; u2 = v2; u3 = v3;
    }

    // out = x - Dt(u_final)
    float upl = __shfl_up(u3, 1);                   // u[4l-1]
    upl = l0 ? 0.f : upl;

    float4 o;
    o.x = x0 - upl + u0;
    o.y = x1 - u0 + u1;
    o.z = x2 - u1 + u2;
    o.w = x3 - u2 + u3;                             // lane63: u3==0 -> x - u[254]
    reinterpret_cast<float4*>(out)[(row << 6) + lane] = o;
}

extern "C" void kernel_launch(void* const* d_in, const int* in_sizes, int n_in,
                              void* d_out, int out_size, void* d_ws, size_t ws_size,
                              hipStream_t stream)
{
    const float* x    = (const float*)d_in[0];
    const float* lmbd = (const float*)d_in[1];
    float* out        = (float*)d_out;

    // t-sequence is data-independent: bake (t_k - 1)/t_{k+1} into kernargs.
    // Computed in fp32 to mirror the reference's fp32 carry.
    Coefs co;
    float t = 1.0f;
    for (int k = 0; k < N_ITERS; ++k) {
        const float tn = 0.5f * (1.0f + sqrtf(1.0f + 4.0f * t * t));
        co.c[k] = (t - 1.0f) / tn;
        t = tn;
    }

    const int rows   = out_size / 256;   // 32768
    const int blocks = rows / 4;         // 4 waves (rows) per 256-thread block
    tv1d_prox_kernel<<<blocks, 256, 0, stream>>>(x, lmbd, out, co);
}

// Round 3
// 109.694 us; speedup vs baseline: 1.1377x; 1.1377x over previous
//
#include <hip/hip_runtime.h>
#include <math.h>

// TV-1D prox via FGP on the dual, 30 fixed iterations.
// One wave64 per row (256 elems); lane l owns elements [4l..4l+3] in regs.
// R3: algebraic refactor (loop-invariant dx = 0.25*D(x)), v_med3 clamp,
// DPP wave_shr/shl shuffles (1 VALU op, zero-fill at wave edge, no LDS).

constexpr int N_ITERS = 30;

struct Coefs { float c[N_ITERS]; };

// lane n <- lane n-1, lane 0 <- 0   (data moves toward higher lanes)
__device__ __forceinline__ float dpp_up1_z(float v) {
    return __int_as_float(__builtin_amdgcn_update_dpp(
        0, __float_as_int(v), 0x138 /*wave_shr:1*/, 0xf, 0xf, true));
}
// lane n <- lane n+1, lane 63 <- 0
__device__ __forceinline__ float dpp_dn1_z(float v) {
    return __int_as_float(__builtin_amdgcn_update_dpp(
        0, __float_as_int(v), 0x130 /*wave_shl:1*/, 0xf, 0xf, true));
}

__global__ __launch_bounds__(256, 8)
void tv1d_prox_kernel(const float* __restrict__ x,
                      const float* __restrict__ lmbd_param,
                      float* __restrict__ out,
                      Coefs co)
{
    const int lane = threadIdx.x & 63;
    const int wave = threadIdx.x >> 6;
    const int row  = (blockIdx.x << 2) | wave;      // 32768 rows total
    const int chan = (row >> 7) & 31;               // dims (8,32,128,256)

    const float p    = lmbd_param[chan];
    const float lam  = log1pf(expf(p));             // softplus
    const float nlam = -lam;

    // coalesced float4 load: lane l reads 16B at row*1KB + 16*l
    const float4 xv = reinterpret_cast<const float4*>(x)[(row << 6) + lane];
    const float x0 = xv.x, x1 = xv.y, x2 = xv.z, x3 = xv.w;
    const float x4 = dpp_dn1_z(x0);                 // halo x[4l+4] (l63: 0, masked later)

    // loop-invariant: dx[j] = 0.25*(x[j+1]-x[j])
    const float dx0 = 0.25f * (x1 - x0);
    const float dx1 = 0.25f * (x2 - x1);
    const float dx2 = 0.25f * (x3 - x2);
    const float dx3 = 0.25f * (x4 - x3);            // l63: garbage, masked every iter

    const bool l63 = (lane == 63);

    // Iteration 0 peeled: y=u=0 -> v = dx; c0 = 0 -> y = u = clip(dx).
    float u0 = __builtin_amdgcn_fmed3f(dx0, nlam, lam);
    float u1 = __builtin_amdgcn_fmed3f(dx1, nlam, lam);
    float u2 = __builtin_amdgcn_fmed3f(dx2, nlam, lam);
    float u3 = __builtin_amdgcn_fmed3f(dx3, nlam, lam);
    u3 = l63 ? 0.f : u3;                            // dummy dual slot u[255] == 0
    float y0 = u0, y1 = u1, y2 = u2, y3 = u3;

#pragma unroll
    for (int it = 1; it < N_ITERS; ++it) {
        const float ypl = dpp_up1_z(y3);            // y[4l-1], lane0 -> 0 (= y[-1])
        const float ynf = dpp_dn1_z(y0);            // y[4l+4], lane63 -> 0 (dummy)

        // v[j] = 0.5*y[j] + dx[j] + 0.25*(y[j-1] + y[j+1])
        const float s0 = ypl + y1;
        const float s1 = y0  + y2;
        const float s2 = y1  + y3;
        const float s3 = y2  + ynf;
        float v0 = fmaf(0.25f, s0, fmaf(0.5f, y0, dx0));
        float v1 = fmaf(0.25f, s1, fmaf(0.5f, y1, dx1));
        float v2 = fmaf(0.25f, s2, fmaf(0.5f, y2, dx2));
        float v3 = fmaf(0.25f, s3, fmaf(0.5f, y3, dx3));
        v0 = __builtin_amdgcn_fmed3f(v0, nlam, lam);
        v1 = __builtin_amdgcn_fmed3f(v1, nlam, lam);
        v2 = __builtin_amdgcn_fmed3f(v2, nlam, lam);
        v3 = __builtin_amdgcn_fmed3f(v3, nlam, lam);
        v3 = l63 ? 0.f : v3;                        // keep dummy slot at 0

        if (it < N_ITERS - 1) {                     // folds at compile time (unrolled)
            const float c = co.c[it];               // y_next = v + c*(v - u_prev)
            y0 = fmaf(c, v0 - u0, v0);
            y1 = fmaf(c, v1 - u1, v1);
            y2 = fmaf(c, v2 - u2, v2);
            y3 = fmaf(c, v3 - u3, v3);
        }
        u0 = v0; u1 = v1; u2 = v2; u3 = v3;
    }

    // out = x - Dt(u_final);  out[i] = x[i] - u[i-1] + u[i]
    const float upl = dpp_up1_z(u3);                // u[4l-1], lane0 -> 0

    float4 o;
    o.x = x0 - upl + u0;
    o.y = x1 - u0 + u1;
    o.z = x2 - u1 + u2;
    o.w = x3 - u2 + u3;                             // lane63: u3==0 -> x - u[254]
    reinterpret_cast<float4*>(out)[(row << 6) + lane] = o;
}

extern "C" void kernel_launch(void* const* d_in, const int* in_sizes, int n_in,
                              void* d_out, int out_size, void* d_ws, size_t ws_size,
                              hipStream_t stream)
{
    const float* x    = (const float*)d_in[0];
    const float* lmbd = (const float*)d_in[1];
    float* out        = (float*)d_out;

    // t-sequence is data-independent: bake (t_k - 1)/t_{k+1} into kernargs.
    Coefs co;
    float t = 1.0f;
    for (int k = 0; k < N_ITERS; ++k) {
        const float tn = 0.5f * (1.0f + sqrtf(1.0f + 4.0f * t * t));
        co.c[k] = (t - 1.0f) / tn;
        t = tn;
    }

    const int rows   = out_size / 256;   // 32768
    const int blocks = rows / 4;         // 4 waves (rows) per 256-thread block
    tv1d_prox_kernel<<<blocks, 256, 0, stream>>>(x, lmbd, out, co);
}

// Round 4
// 105.758 us; speedup vs baseline: 1.1801x; 1.0372x over previous
//
#include <hip/hip_runtime.h>
#include <math.h>

// TV-1D prox via FGP on the dual, 30 fixed iterations.
// One wave64 per row (256 elems); lane l owns elements [4l..4l+3] in regs.
// R4: shifts moved off the VALU port onto the LDS pipe (ds_bpermute with
// hoisted indices); lane-63 dummy-slot mask folded into its med3 clamp
// bounds (lam3 = 0 on lane 63). Per-iter VALU: 27 -> 25.

constexpr int N_ITERS = 30;

struct Coefs { float c[N_ITERS]; };

// lane n <- lane n+1, lane 63 <- 0 (one-time x halo only)
__device__ __forceinline__ float dpp_dn1_z(float v) {
    return __int_as_float(__builtin_amdgcn_update_dpp(
        0, __float_as_int(v), 0x130 /*wave_shl:1*/, 0xf, 0xf, true));
}
// LDS-pipe lane gather: lane i <- lane (idx>>2)&63
__device__ __forceinline__ float bperm(int idx, float v) {
    return __int_as_float(__builtin_amdgcn_ds_bpermute(idx, __float_as_int(v)));
}

__global__ __launch_bounds__(256, 8)
void tv1d_prox_kernel(const float* __restrict__ x,
                      const float* __restrict__ lmbd_param,
                      float* __restrict__ out,
                      Coefs co)
{
    const int lane = threadIdx.x & 63;
    const int wave = threadIdx.x >> 6;
    const int row  = (blockIdx.x << 2) | wave;      // 32768 rows total
    const int chan = (row >> 7) & 31;               // dims (8,32,128,256)

    const float p    = lmbd_param[chan];
    const float lam  = log1pf(expf(p));             // softplus (unchanged numerics)
    const float nlam = -lam;

    // shift indices, hoisted: bits[7:2] select source lane (mod 64)
    const int idx_up = (lane << 2) - 4;             // lane-1 (lane0 wraps -> masked)
    const int idx_dn = (lane << 2) + 4;             // lane+1 (lane63 wraps -> benign)

    // slot-3 clamp bounds: 0 on lane 63 => med3 pins the dummy dual slot to 0
    const bool l0  = (lane == 0);
    const bool l63 = (lane == 63);
    const float lam3  = l63 ? 0.f : lam;
    const float nlam3 = -lam3;

    // coalesced float4 load: lane l reads 16B at row*1KB + 16*l
    const float4 xv = reinterpret_cast<const float4*>(x)[(row << 6) + lane];
    const float x0 = xv.x, x1 = xv.y, x2 = xv.z, x3 = xv.w;
    const float x4 = dpp_dn1_z(x0);                 // halo x[4l+4] (l63: 0)

    // loop-invariant: dx[j] = 0.25*(x[j+1]-x[j])
    const float dx0 = 0.25f * (x1 - x0);
    const float dx1 = 0.25f * (x2 - x1);
    const float dx2 = 0.25f * (x3 - x2);
    const float dx3 = 0.25f * (x4 - x3);            // l63: finite garbage -> med3 -> 0

    // Iteration 0 peeled: y=u=0 -> v = dx; c0 = 0 -> y = u = clip(dx).
    float u0 = __builtin_amdgcn_fmed3f(dx0, nlam, lam);
    float u1 = __builtin_amdgcn_fmed3f(dx1, nlam, lam);
    float u2 = __builtin_amdgcn_fmed3f(dx2, nlam, lam);
    float u3 = __builtin_amdgcn_fmed3f(dx3, nlam3, lam3);   // lane63 -> 0
    float y0 = u0, y1 = u1, y2 = u2, y3 = u3;

#pragma unroll
    for (int it = 1; it < N_ITERS; ++it) {
        const float ypl_raw = bperm(idx_up, y3);    // y[4l-1]  (LDS pipe)
        const float ynf     = bperm(idx_dn, y0);    // y[4l+4]  (LDS pipe; l63 benign)
        const float ypl = l0 ? 0.f : ypl_raw;       // Dt boundary y[-1] = 0

        // v[j] = 0.5*y[j] + dx[j] + 0.25*(y[j-1] + y[j+1])
        const float s0 = ypl + y1;
        const float s1 = y0  + y2;
        const float s2 = y1  + y3;
        const float s3 = y2  + ynf;
        float v0 = fmaf(0.25f, s0, fmaf(0.5f, y0, dx0));
        float v1 = fmaf(0.25f, s1, fmaf(0.5f, y1, dx1));
        float v2 = fmaf(0.25f, s2, fmaf(0.5f, y2, dx2));
        float v3 = fmaf(0.25f, s3, fmaf(0.5f, y3, dx3));
        v0 = __builtin_amdgcn_fmed3f(v0, nlam, lam);
        v1 = __builtin_amdgcn_fmed3f(v1, nlam, lam);
        v2 = __builtin_amdgcn_fmed3f(v2, nlam, lam);
        v3 = __builtin_amdgcn_fmed3f(v3, nlam3, lam3);      // lane63 pinned to 0

        if (it < N_ITERS - 1) {                     // folds at compile time (unrolled)
            const float c = co.c[it];               // y_next = v + c*(v - u_prev)
            y0 = fmaf(c, v0 - u0, v0);
            y1 = fmaf(c, v1 - u1, v1);
            y2 = fmaf(c, v2 - u2, v2);
            y3 = fmaf(c, v3 - u3, v3);
        }
        u0 = v0; u1 = v1; u2 = v2; u3 = v3;
    }

    // out = x - Dt(u_final);  out[i] = x[i] - u[i-1] + u[i]
    const float upl_raw = bperm(idx_up, u3);        // u[4l-1]
    const float upl = l0 ? 0.f : upl_raw;

    float4 o;
    o.x = x0 - upl + u0;
    o.y = x1 - u0 + u1;
    o.z = x2 - u1 + u2;
    o.w = x3 - u2 + u3;                             // lane63: u3==+-0 -> x - u[254]
    reinterpret_cast<float4*>(out)[(row << 6) + lane] = o;
}

extern "C" void kernel_launch(void* const* d_in, const int* in_sizes, int n_in,
                              void* d_out, int out_size, void* d_ws, size_t ws_size,
                              hipStream_t stream)
{
    const float* x    = (const float*)d_in[0];
    const float* lmbd = (const float*)d_in[1];
    float* out        = (float*)d_out;

    // t-sequence is data-independent: bake (t_k - 1)/t_{k+1} into kernargs.
    Coefs co;
    float t = 1.0f;
    for (int k = 0; k < N_ITERS; ++k) {
        const float tn = 0.5f * (1.0f + sqrtf(1.0f + 4.0f * t * t));
        co.c[k] = (t - 1.0f) / tn;
        t = tn;
    }

    const int rows   = out_size / 256;   // 32768
    const int blocks = rows / 4;         // 4 waves (rows) per 256-thread block
    tv1d_prox_kernel<<<blocks, 256, 0, stream>>>(x, lmbd, out, co);
}

// Round 5
// 103.167 us; speedup vs baseline: 1.2097x; 1.0251x over previous
//
#include <hip/hip_runtime.h>
#include <math.h>

// TV-1D prox via FGP on the dual, 30 fixed iterations.
// One wave64 per row (256 elems); lane l owns elements [4l..4l+3] in regs.
// R5: zero remaining boundary masks. Invariant: dual slot (lane63, j=3) is
// pinned to +-0 every iteration by its med3 bounds (lam3=0). The up-shift
// ds_bpermute on lane 0 (idx = -4, addr bits[7:2] wrap to 63) therefore
// reads exactly that pinned slot -> y[-1]=0 for free, no cndmask.
// Loop body = 24 VALU (the 6-op/elem structural floor) + 2 LDS-pipe ops.

constexpr int N_ITERS = 30;

struct Coefs { float c[N_ITERS]; };

// lane n <- lane n+1, lane 63 <- 0 (one-time x halo only)
__device__ __forceinline__ float dpp_dn1_z(float v) {
    return __int_as_float(__builtin_amdgcn_update_dpp(
        0, __float_as_int(v), 0x130 /*wave_shl:1*/, 0xf, 0xf, true));
}
// LDS-pipe lane gather: lane i <- lane (idx>>2)&63
__device__ __forceinline__ float bperm(int idx, float v) {
    return __int_as_float(__builtin_amdgcn_ds_bpermute(idx, __float_as_int(v)));
}

__global__ __launch_bounds__(256, 8)
void tv1d_prox_kernel(const float* __restrict__ x,
                      const float* __restrict__ lmbd_param,
                      float* __restrict__ out,
                      Coefs co)
{
    const int lane = threadIdx.x & 63;
    const int wave = threadIdx.x >> 6;
    const int row  = (blockIdx.x << 2) | wave;      // 32768 rows total
    const int chan = (row >> 7) & 31;               // dims (8,32,128,256)

    const float p    = lmbd_param[chan];
    const float lam  = log1pf(expf(p));             // softplus (unchanged numerics)
    const float nlam = -lam;

    // shift indices, hoisted: bperm uses addr bits[7:2] (wraps mod 64 lanes)
    const int idx_up = (lane << 2) - 4;             // lane-1; lane0 -> lane63 (pinned 0)
    const int idx_dn = (lane << 2) + 4;             // lane+1; lane63 -> lane0 (masked by lam3)

    // slot-3 clamp bounds: 0 on lane 63 => med3 pins the dummy dual slot to +-0
    const bool l63 = (lane == 63);
    const float lam3  = l63 ? 0.f : lam;
    const float nlam3 = -lam3;

    // coalesced float4 load: lane l reads 16B at row*1KB + 16*l
    const float4 xv = reinterpret_cast<const float4*>(x)[(row << 6) + lane];
    const float x0 = xv.x, x1 = xv.y, x2 = xv.z, x3 = xv.w;
    const float x4 = dpp_dn1_z(x0);                 // halo x[4l+4] (l63: 0)

    // loop-invariant: dx[j] = 0.25*(x[j+1]-x[j])
    const float dx0 = 0.25f * (x1 - x0);
    const float dx1 = 0.25f * (x2 - x1);
    const float dx2 = 0.25f * (x3 - x2);
    const float dx3 = 0.25f * (x4 - x3);            // l63: finite garbage -> med3 -> 0

    // Iteration 0 peeled: y=u=0 -> v = dx; c0 = 0 -> y = u = clip(dx).
    float u0 = __builtin_amdgcn_fmed3f(dx0, nlam, lam);
    float u1 = __builtin_amdgcn_fmed3f(dx1, nlam, lam);
    float u2 = __builtin_amdgcn_fmed3f(dx2, nlam, lam);
    float u3 = __builtin_amdgcn_fmed3f(dx3, nlam3, lam3);   // lane63 -> +-0
    float y0 = u0, y1 = u1, y2 = u2, y3 = u3;

#pragma unroll
    for (int it = 1; it < N_ITERS; ++it) {
        const float ypl = bperm(idx_up, y3);        // y[4l-1]; lane0 reads pinned +-0
        const float ynf = bperm(idx_dn, y0);        // y[4l+4]; lane63 garbage -> pinned

        // v[j] = 0.5*y[j] + dx[j] + 0.25*(y[j-1] + y[j+1])
        const float s0 = ypl + y1;
        const float s1 = y0  + y2;
        const float s2 = y1  + y3;
        const float s3 = y2  + ynf;
        float v0 = fmaf(0.25f, s0, fmaf(0.5f, y0, dx0));
        float v1 = fmaf(0.25f, s1, fmaf(0.5f, y1, dx1));
        float v2 = fmaf(0.25f, s2, fmaf(0.5f, y2, dx2));
        float v3 = fmaf(0.25f, s3, fmaf(0.5f, y3, dx3));
        v0 = __builtin_amdgcn_fmed3f(v0, nlam, lam);
        v1 = __builtin_amdgcn_fmed3f(v1, nlam, lam);
        v2 = __builtin_amdgcn_fmed3f(v2, nlam, lam);
        v3 = __builtin_amdgcn_fmed3f(v3, nlam3, lam3);      // lane63 pinned to +-0

        if (it < N_ITERS - 1) {                     // folds at compile time (unrolled)
            const float c = co.c[it];               // y_next = v + c*(v - u_prev)
            y0 = fmaf(c, v0 - u0, v0);
            y1 = fmaf(c, v1 - u1, v1);
            y2 = fmaf(c, v2 - u2, v2);
            y3 = fmaf(c, v3 - u3, v3);              // lane63: stays +-0
        }
        u0 = v0; u1 = v1; u2 = v2; u3 = v3;
    }

    // out = x - Dt(u_final);  out[i] = x[i] - u[i-1] + u[i]
    const float upl = bperm(idx_up, u3);            // lane0 reads pinned +-0

    float4 o;
    o.x = x0 - upl + u0;
    o.y = x1 - u0 + u1;
    o.z = x2 - u1 + u2;
    o.w = x3 - u2 + u3;                             // lane63: u3==+-0 -> x - u[254]
    reinterpret_cast<float4*>(out)[(row << 6) + lane] = o;
}

extern "C" void kernel_launch(void* const* d_in, const int* in_sizes, int n_in,
                              void* d_out, int out_size, void* d_ws, size_t ws_size,
                              hipStream_t stream)
{
    const float* x    = (const float*)d_in[0];
    const float* lmbd = (const float*)d_in[1];
    float* out        = (float*)d_out;

    // t-sequence is data-independent: bake (t_k - 1)/t_{k+1} into kernargs.
    Coefs co;
    float t = 1.0f;
    for (int k = 0; k < N_ITERS; ++k) {
        const float tn = 0.5f * (1.0f + sqrtf(1.0f + 4.0f * t * t));
        co.c[k] = (t - 1.0f) / tn;
        t = tn;
    }

    const int rows   = out_size / 256;   // 32768
    const int blocks = rows / 4;         // 4 waves (rows) per 256-thread block
    tv1d_prox_kernel<<<blocks, 256, 0, stream>>>(x, lmbd, out, co);
}